// Round 6
// baseline (377.869 us; speedup 1.0000x reference)
//
#include <hip/hip_runtime.h>
#include <stdint.h>

// ---------------------------------------------------------------------------
// MixingLayer: b=16, m=64, f=128, k=64, L2=16, LMAX=4. ALL I/O IS FP32.
// SEG = [0,1,1,1,2,2,2,2,2,3,3,3,3,3,3,3]
//
// Round-13: R2 (46.2 us, proven) restructured for 4 blocks/CU.
//   * Issue-at-top pipeline: B(t+1)/Y(t+2) DMAs are the FIRST instructions
//     of step t; the end-of-step __syncthreads() drains them ~a full step
//     later (>= L2 latency) -> prefetch overlap without counted vmcnt.
//   * 2 buffers everywhere: sA[2]+sB[2]+yS[2] = 40960 B exactly
//     -> 4 blocks/CU; __launch_bounds__(512,8) (R2 used 56 VGPR) -> 32
//     waves/CU. 4 independent barrier groups per CU decouple the step
//     convoy that capped R1/R2 at 2 streams/CU.
//   * Step body (computeG, writeA swizzle, a/b reads, MFMA, C-store),
//     convert_all, finish_kernel: byte-identical to R2.
//
// ws layout (bytes):
//   Wb2 bf16 [16fb][128fy][128n][32] @ 0        (16,777,216)
//   xb  bf16 [1024 m][128 f][16] @ 16777216     ( 4,194,304)
//   yb  bf16 [1024 m][128 f][16] @ 20971520     ( 4,194,304)
//   Cpart f32 [64][1024][128]    @ 25165824     (33,554,432)
//   wfT f32 [2][64 k][4 l][128f] @ 58720256     (   262,144)
// ---------------------------------------------------------------------------

#define AS1 __attribute__((address_space(1)))
#define AS3 __attribute__((address_space(3)))

typedef __bf16 bf16x8 __attribute__((ext_vector_type(8)));
typedef float f32x4 __attribute__((ext_vector_type(4)));

__device__ __forceinline__ uint16_t f2b(float f) {
  uint32_t u = __float_as_uint(f);
  u += 0x7fffu + ((u >> 16) & 1u);   // RNE
  return (uint16_t)(u >> 16);
}

#if __has_builtin(__builtin_amdgcn_fdot2_f32_bf16)
typedef __bf16 bf16x2 __attribute__((ext_vector_type(2)));
__device__ __forceinline__ float dot2b(uint32_t a, uint32_t b, float c) {
  union { uint32_t u; bf16x2 v; } ua, ub;
  ua.u = a; ub.u = b;
  return __builtin_amdgcn_fdot2_f32_bf16(ua.v, ub.v, c, false);
}
#else
__device__ __forceinline__ float dot2b(uint32_t a, uint32_t b, float c) {
  float a0 = __uint_as_float(a << 16), a1 = __uint_as_float(a & 0xffff0000u);
  float b0 = __uint_as_float(b << 16), b1 = __uint_as_float(b & 0xffff0000u);
  return c + a0 * b0 + a1 * b1;
}
#endif

// ---------------------------------------------------------------------------
// K0: Wb2 (blocked, swizzle-baked) + xb/yb bf16 + wfT transpose. (R2 exact)
// grid: [0,4096) Wb2 ; [4096,6144) xb/yb ; [6144,6176) wfT.
// ---------------------------------------------------------------------------
__global__ __launch_bounds__(256) void convert_all(
    const float* __restrict__ wx0, const float* __restrict__ wy0,
    const float* __restrict__ x, const float* __restrict__ y,
    const float* __restrict__ wxf, const float* __restrict__ wyf,
    uint16_t* __restrict__ Wb2, uint16_t* __restrict__ xb,
    uint16_t* __restrict__ yb, float* __restrict__ wfT) {
  int bid = blockIdx.x, tid = threadIdx.x;
  if (bid < 4096) {  // Wb2: 1,048,576 chunks of 8 halves
    int c = bid * 256 + tid;
    int fb = c >> 16;
    int rem = c & 65535;
    int fy = rem >> 9;
    int rem2 = rem & 511;
    int n = rem2 >> 2, pos = rem2 & 3;
    int slot = pos ^ ((n >> 1) & 3);   // bake the sB read swizzle
    int k = n & 63;
    const float* src = (n < 64 ? wx0 : wy0) +
        ((size_t)(k * 128 + fy) * 512 + fb * 32 + slot * 8);
    float4 v0 = *(const float4*)src;
    float4 v1 = *(const float4*)(src + 4);
    uint32_t o0 = (uint32_t)f2b(v0.x) | ((uint32_t)f2b(v0.y) << 16);
    uint32_t o1 = (uint32_t)f2b(v0.z) | ((uint32_t)f2b(v0.w) << 16);
    uint32_t o2 = (uint32_t)f2b(v1.x) | ((uint32_t)f2b(v1.y) << 16);
    uint32_t o3 = (uint32_t)f2b(v1.z) | ((uint32_t)f2b(v1.w) << 16);
    *(uint4*)(Wb2 + (size_t)c * 8) = make_uint4(o0, o1, o2, o3);
    return;
  }
  if (bid >= 6144) {  // wfT: 32 blocks x 256 thr x 8 elems = 65536
    int base = (bid - 6144) * 2048 + tid * 8;
#pragma unroll
    for (int ii = 0; ii < 8; ++ii) {
      int idx = base + ii;
      int side = idx >> 15, rem = idx & 32767;
      int k = rem >> 9, l = (rem >> 7) & 3, f = rem & 127;
      const float* src = side ? wyf : wxf;
      wfT[idx] = src[((size_t)l * 128 + f) * 64 + k];
    }
    return;
  }
  size_t i = ((size_t)(bid - 4096) * 256 + tid) * 8;
  const float* s; uint16_t* d;
  if (i < 2097152) { s = x + i;             d = xb + i; }
  else             { s = y + (i - 2097152); d = yb + (i - 2097152); }
  float4 v0 = *(const float4*)s;
  float4 v1 = *(const float4*)(s + 4);
  uint32_t o0 = (uint32_t)f2b(v0.x) | ((uint32_t)f2b(v0.y) << 16);
  uint32_t o1 = (uint32_t)f2b(v0.z) | ((uint32_t)f2b(v0.w) << 16);
  uint32_t o2 = (uint32_t)f2b(v1.x) | ((uint32_t)f2b(v1.y) << 16);
  uint32_t o3 = (uint32_t)f2b(v1.z) | ((uint32_t)f2b(v1.w) << 16);
  *(uint4*)d = make_uint4(o0, o1, o2, o3);
}

// ---------------------------------------------------------------------------
// K1: FUSED G-gen + split GEMM, 8 waves, issue-at-top + __syncthreads.
// grid (64 groups, 8 M-tiles); group g: fb = g>>2, fyg = g&3 (32 fy).
// 32 steps, step t: fy = fyg*32 + t. 2-buffered, 40960 B LDS, 4 blocks/CU.
// ---------------------------------------------------------------------------
__device__ __forceinline__ void gload_lds16(const void* g, void* l) {
  __builtin_amdgcn_global_load_lds((const AS1 uint32_t*)g, (AS3 uint32_t*)l, 16, 0, 0);
}

__global__ __launch_bounds__(512, 8) void fused_gemm(
    const uint16_t* __restrict__ xb, const uint16_t* __restrict__ yb,
    const uint16_t* __restrict__ Wb2, float* __restrict__ Cpart) {
  __shared__ __align__(16) uint16_t sA[2][128 * 32];  // XOR slot swizzle
  __shared__ __align__(16) uint16_t sB[2][128 * 32];  // swizzle baked in Wb2
  __shared__ __align__(16) uint16_t yS[2][2048];      // [chunk(2)][m(128)][8c]

  int tid = threadIdx.x;
  int w = tid >> 6, lane = tid & 63;
  int g_id = blockIdx.x;            // 0..63
  int fb = g_id >> 2, fyg = g_id & 3;
  int FB = fb * 8;
  int fy0 = fyg * 32;
  int m0 = blockIdx.y * 128;
  int r = lane & 15, q = lane >> 4;
  int wm = w >> 2, wn = w & 3;      // 2 x 4 wave grid over 128m x 128n
  int m_loc = tid & 127, quarter = tid >> 7;

  // ---- one-time: x[m, FB+quarter*2 .. +2, 0:16] packed into 16 dwords
  uint32_t xr[16];
  {
    const uint16_t* xp0 = xb + (size_t)(m0 + m_loc) * 2048 + (FB + quarter * 2) * 16;
#pragma unroll
    for (int j = 0; j < 4; ++j) {
      uint4 v = *(const uint4*)(xp0 + j * 8);
      xr[j * 4 + 0] = v.x; xr[j * 4 + 1] = v.y;
      xr[j * 4 + 2] = v.z; xr[j * 4 + 3] = v.w;
    }
  }

  f32x4 zero = {0.f, 0.f, 0.f, 0.f};
  f32x4 acc[4][2];
#pragma unroll
  for (int i = 0; i < 4; ++i)
#pragma unroll
    for (int j = 0; j < 2; ++j) acc[i][j] = zero;

  // ---- DMA roles: every wave stages one 1-KB B chunk; waves 0-3 also
  //      stage one 1-KB Y chunk. All issued at TOP of each step.
  auto issueB = [&](uint16_t* dstB, int t) {
    size_t base = (size_t)(fb * 128 + fy0 + t) * 4096;  // halves
    gload_lds16(Wb2 + base + (size_t)w * 512 + lane * 8, dstB + w * 512);
  };
  int ychunk = (w >> 1) & 1, ymbase = (w & 1) * 64;
  const uint16_t* ysrc_base = yb + (size_t)(m0 + ymbase + lane) * 2048 + ychunk * 8;
  int ydst_off = ychunk * 1024 + ymbase * 8;  // + lane*8 implied by DMA
  auto issueY = [&](uint16_t* dstY, int t) {
    if (w < 4) gload_lds16(ysrc_base + (size_t)(fy0 + t) * 16, dstY + ydst_off);
  };

  auto computeG = [&](const uint16_t* srcY, float* gg) {
    uint4 ya = *(const uint4*)(srcY + m_loc * 8);
    uint4 yc = *(const uint4*)(srcY + 1024 + m_loc * 8);
    uint32_t yp[8] = {ya.x, ya.y, ya.z, ya.w, yc.x, yc.y, yc.z, yc.w};
    uint32_t yl0 = yp[0] & 0xffffu, yh0 = yp[0] & 0xffff0000u;
    uint32_t yl4 = yp[4] & 0xffffu, yh4 = yp[4] & 0xffff0000u;
#pragma unroll
    for (int fxp = 0; fxp < 2; ++fxp) {
      const uint32_t* xp = xr + fxp * 8;
      gg[fxp * 4 + 0] = dot2b(xp[0], yl0, 0.f);
      gg[fxp * 4 + 1] = dot2b(xp[1], yp[1], dot2b(xp[0], yh0, 0.f));
      gg[fxp * 4 + 2] = dot2b(xp[4], yl4,
                         dot2b(xp[3], yp[3], dot2b(xp[2], yp[2], 0.f)));
      gg[fxp * 4 + 3] = dot2b(xp[7], yp[7], dot2b(xp[6], yp[6],
                         dot2b(xp[5], yp[5], dot2b(xp[4], yh4, 0.f))));
    }
  };
  auto writeA = [&](uint16_t* dstA, const float* gg) {
    uint32_t o[4];
#pragma unroll
    for (int p = 0; p < 4; ++p)
      o[p] = (__float_as_uint(gg[2 * p]) >> 16) |
             (__float_as_uint(gg[2 * p + 1]) & 0xffff0000u);
    int pos = quarter ^ ((m_loc >> 1) & 3);   // XOR slot swizzle
    *(uint4*)(dstA + m_loc * 32 + pos * 8) = make_uint4(o[0], o[1], o[2], o[3]);
  };

  float gg[8];
  // ---- prologue: Y(0),Y(1),B(0) staged; A(0) computed; 2 barriers.
  issueY(yS[0], 0);
  issueY(yS[1], 1);
  issueB(sB[0], 0);
  __syncthreads();                 // drains all (incl. xr loads)
  computeG(yS[0], gg);
  writeA(sA[0], gg);
  __syncthreads();                 // A(0) visible

  for (int t = 0; t < 32; ++t) {
    uint16_t* pAc = sA[t & 1];
    uint16_t* pBc = sB[t & 1];
    // top-of-step issues: land by this step's closing barrier
    if (t < 31) issueB(sB[(t + 1) & 1], t + 1);
    if (t < 30) issueY(yS[t & 1], t + 2);

    bf16x8 a[4], b[2];
#pragma unroll
    for (int i = 0; i < 4; ++i) {
      int row = wm * 64 + i * 16 + r;
      int pos = q ^ ((row >> 1) & 3);
      a[i] = *(const bf16x8*)&pAc[row * 32 + pos * 8];
    }
#pragma unroll
    for (int j = 0; j < 2; ++j) {
      int row = wn * 32 + j * 16 + r;
      int pos = q ^ ((row >> 1) & 3);
      b[j] = *(const bf16x8*)&pBc[row * 32 + pos * 8];
    }

    if (t < 31) {                 // produce A(t+1) from Y(t+1)
      computeG(yS[(t + 1) & 1], gg);
      writeA(sA[(t + 1) & 1], gg);
    }

    __builtin_amdgcn_s_setprio(1);
#pragma unroll
    for (int i = 0; i < 4; ++i)
#pragma unroll
      for (int j = 0; j < 2; ++j)
        acc[i][j] = __builtin_amdgcn_mfma_f32_16x16x32_bf16(a[i], b[j], acc[i][j], 0, 0, 0);
    __builtin_amdgcn_s_setprio(0);

    if (t < 31) __syncthreads();  // drains DMAs (full step of flight) + LDS
  }

  // C/D layout: col(n)=lane&15, row(m)=(lane>>4)*4+reg
  float* cbase = Cpart + (size_t)g_id * 131072;  // 1024*128 per partial
#pragma unroll
  for (int i = 0; i < 4; ++i)
#pragma unroll
    for (int j = 0; j < 2; ++j)
#pragma unroll
      for (int reg = 0; reg < 4; ++reg) {
        int mm = m0 + wm * 64 + i * 16 + q * 4 + reg;
        int nn = wn * 32 + j * 16 + r;
        cbase[(size_t)mm * 128 + nn] = acc[i][j][reg];
      }
}

// ---------------------------------------------------------------------------
// K2: ONE BLOCK PER bm: inline 64-partial reduce, MLP, gates via wfT, output.
// ---------------------------------------------------------------------------
__global__ __launch_bounds__(256) void finish_kernel(
    const float* __restrict__ x, const float* __restrict__ y,
    const float* __restrict__ wx_mlp, const float* __restrict__ bx_mlp,
    const float* __restrict__ wy_mlp, const float* __restrict__ by_mlp,
    const float* __restrict__ wfT,
    const float* __restrict__ Cpart, float* __restrict__ out) {
  const int seg[16] = {0,1,1,1,2,2,2,2,2,3,3,3,3,3,3,3};
  __shared__ float sred[256];
  __shared__ float sm[128];
  __shared__ float sg[2][128][4];
  int t = threadIdx.x;
  int bm = blockIdx.x;
  int mi = bm & 63;

  {  // inline split-K reduction: sm[n] = sum_{sp<64} Cpart[sp][bm][n]
    int col = t & 127, hh = t >> 7;
    const float* cp = Cpart + (size_t)(hh * 32) * 131072 + (size_t)bm * 128 + col;
    float s = 0.f;
#pragma unroll 8
    for (int sp = 0; sp < 32; ++sp)
      s += cp[(size_t)sp * 131072];
    sred[t] = s;
  }
  __syncthreads();
  if (t < 128) sm[t] = sred[t] + sred[t + 128];  // [0:64)=mx, [64:128)=my
  __syncthreads();

  for (int st = 0; st < 2; ++st) {
    float v = 0.f;
    if (t < 128) {
      int side = t >> 6, j = t & 63;
      const float* wmlp = side ? wy_mlp : wx_mlp;
      const float* bmlp = side ? by_mlp : bx_mlp;
      const float* mv = sm + side * 64;
#pragma unroll 8
      for (int k = 0; k < 64; ++k)
        v += mv[k] * wmlp[(st * 64 + k) * 64 + j];
      v += bmlp[(st * 64 + mi) * 64 + j];
      v = v / (1.f + __expf(-v));
    }
    __syncthreads();
    if (t < 128) sm[t] = v;
    __syncthreads();
  }

  {  // gates: side wave-uniform, coalesced wfT reads
    int side = t >> 7, f = t & 127;
    const float* base = wfT + side * 32768;  // [k][l][f]
    const float* mv = sm + side * 64;
    float gg[4] = {0.f, 0.f, 0.f, 0.f};
#pragma unroll 8
    for (int k = 0; k < 64; ++k) {
      float m2 = mv[k];
#pragma unroll
      for (int l = 0; l < 4; ++l)
        gg[l] += m2 * base[(k * 4 + l) * 128 + f];
    }
#pragma unroll
    for (int l = 0; l < 4; ++l)
      sg[side][f][l] = gg[l] / (1.f + __expf(-gg[l]));
  }
  __syncthreads();

  {  // output: thread -> (f, half), 8 floats; fully coalesced
    int f = t >> 1, half = t & 1;
    size_t base = ((size_t)bm * 128 + f) * 16 + half * 8;
    float4 xa = *(const float4*)(x + base), xb4 = *(const float4*)(x + base + 4);
    float4 ya = *(const float4*)(y + base), yb4 = *(const float4*)(y + base + 4);
    float xv[8] = {xa.x, xa.y, xa.z, xa.w, xb4.x, xb4.y, xb4.z, xb4.w};
    float yv[8] = {ya.x, ya.y, ya.z, ya.w, yb4.x, yb4.y, yb4.z, yb4.w};
    float o[8];
#pragma unroll
    for (int ii = 0; ii < 8; ++ii) {
      int c = half * 8 + ii;
      o[ii] = sg[0][f][seg[c]] * xv[ii] + sg[1][f][seg[c]] * yv[ii];
    }
    *(float4*)(out + base)     = make_float4(o[0], o[1], o[2], o[3]);
    *(float4*)(out + base + 4) = make_float4(o[4], o[5], o[6], o[7]);
  }
}

// ---------------------------------------------------------------------------
extern "C" void kernel_launch(void* const* d_in, const int* in_sizes, int n_in,
                              void* d_out, int out_size, void* d_ws, size_t ws_size,
                              hipStream_t stream) {
  const float* x      = (const float*)d_in[0];
  const float* y      = (const float*)d_in[1];
  const float* wx0    = (const float*)d_in[2];
  const float* wy0    = (const float*)d_in[3];
  const float* wx_mlp = (const float*)d_in[4];
  const float* bx_mlp = (const float*)d_in[5];
  const float* wy_mlp = (const float*)d_in[6];
  const float* by_mlp = (const float*)d_in[7];
  const float* wxf    = (const float*)d_in[8];
  const float* wyf    = (const float*)d_in[9];
  float* out = (float*)d_out;

  uint16_t* Wb2   = (uint16_t*)d_ws;                               // 16,777,216 B
  uint16_t* xb    = (uint16_t*)((char*)d_ws + (size_t)16777216);   //  4,194,304 B
  uint16_t* yb    = (uint16_t*)((char*)d_ws + (size_t)20971520);   //  4,194,304 B
  float*    Cpart = (float*)((char*)d_ws + (size_t)25165824);      // 33,554,432 B
  float*    wfT   = (float*)((char*)d_ws + (size_t)58720256);      //    262,144 B

  convert_all<<<6176, 256, 0, stream>>>(wx0, wy0, x, y, wxf, wyf, Wb2, xb, yb, wfT);
  fused_gemm<<<dim3(64, 8), 512, 0, stream>>>(xb, yb, Wb2, Cpart);
  finish_kernel<<<1024, 256, 0, stream>>>(x, y, wx_mlp, bx_mlp, wy_mlp, by_mlp,
                                          wfT, Cpart, out);
}

// Round 7
// 166.078 us; speedup vs baseline: 2.2753x; 2.2753x over previous
//
#include <hip/hip_runtime.h>
#include <stdint.h>

// ---------------------------------------------------------------------------
// MixingLayer: b=16, m=64, f=128, k=64, L2=16, LMAX=4. ALL I/O IS FP32.
// SEG = [0,1,1,1,2,2,2,2,2,3,3,3,3,3,3,3]
//
// Round-14: restore proven round-9 fused (46.0 us) + Cpart transposed to
// [bm][sp][n] so finish_kernel's split-K reduce is a contiguous 32 KB
// stream per block (was 64 scattered 512B reads at 512KB stride).
// fused's C-store coalescing is unchanged (same 4x64B segments/instr).
// R6 lesson: this kernel needs ~90 regs -> never more than 4 waves/EU.
//
// ws layout (bytes):
//   Wb2 bf16 [16fb][128fy][128n][32] @ 0        (16,777,216)
//   xb  bf16 [1024 m][128 f][16] @ 16777216     ( 4,194,304)
//   yb  bf16 [1024 m][128 f][16] @ 20971520     ( 4,194,304)
//   Cpart f32 [1024 bm][64 sp][128 n] @ 25165824 (33,554,432)
//   wfT f32 [2][64 k][4 l][128f] @ 58720256     (   262,144)
// ---------------------------------------------------------------------------

#define AS1 __attribute__((address_space(1)))
#define AS3 __attribute__((address_space(3)))

typedef __bf16 bf16x8 __attribute__((ext_vector_type(8)));
typedef float f32x4 __attribute__((ext_vector_type(4)));

__device__ __forceinline__ uint16_t f2b(float f) {
  uint32_t u = __float_as_uint(f);
  u += 0x7fffu + ((u >> 16) & 1u);   // RNE
  return (uint16_t)(u >> 16);
}

#if __has_builtin(__builtin_amdgcn_fdot2_f32_bf16)
typedef __bf16 bf16x2 __attribute__((ext_vector_type(2)));
__device__ __forceinline__ float dot2b(uint32_t a, uint32_t b, float c) {
  union { uint32_t u; bf16x2 v; } ua, ub;
  ua.u = a; ub.u = b;
  return __builtin_amdgcn_fdot2_f32_bf16(ua.v, ub.v, c, false);
}
#else
__device__ __forceinline__ float dot2b(uint32_t a, uint32_t b, float c) {
  float a0 = __uint_as_float(a << 16), a1 = __uint_as_float(a & 0xffff0000u);
  float b0 = __uint_as_float(b << 16), b1 = __uint_as_float(b & 0xffff0000u);
  return c + a0 * b0 + a1 * b1;
}
#endif

// ---------------------------------------------------------------------------
// K0: Wb2 (blocked, swizzle-baked) + xb/yb bf16 + wfT transpose.
// grid: [0,4096) Wb2 ; [4096,6144) xb/yb ; [6144,6176) wfT.
// ---------------------------------------------------------------------------
__global__ __launch_bounds__(256) void convert_all(
    const float* __restrict__ wx0, const float* __restrict__ wy0,
    const float* __restrict__ x, const float* __restrict__ y,
    const float* __restrict__ wxf, const float* __restrict__ wyf,
    uint16_t* __restrict__ Wb2, uint16_t* __restrict__ xb,
    uint16_t* __restrict__ yb, float* __restrict__ wfT) {
  int bid = blockIdx.x, tid = threadIdx.x;
  if (bid < 4096) {  // Wb2: 1,048,576 chunks of 8 halves
    int c = bid * 256 + tid;
    int fb = c >> 16;
    int rem = c & 65535;
    int fy = rem >> 9;
    int rem2 = rem & 511;
    int n = rem2 >> 2, pos = rem2 & 3;
    int slot = pos ^ ((n >> 1) & 3);   // bake the sB read swizzle
    int k = n & 63;
    const float* src = (n < 64 ? wx0 : wy0) +
        ((size_t)(k * 128 + fy) * 512 + fb * 32 + slot * 8);
    float4 v0 = *(const float4*)src;
    float4 v1 = *(const float4*)(src + 4);
    uint32_t o0 = (uint32_t)f2b(v0.x) | ((uint32_t)f2b(v0.y) << 16);
    uint32_t o1 = (uint32_t)f2b(v0.z) | ((uint32_t)f2b(v0.w) << 16);
    uint32_t o2 = (uint32_t)f2b(v1.x) | ((uint32_t)f2b(v1.y) << 16);
    uint32_t o3 = (uint32_t)f2b(v1.z) | ((uint32_t)f2b(v1.w) << 16);
    *(uint4*)(Wb2 + (size_t)c * 8) = make_uint4(o0, o1, o2, o3);
    return;
  }
  if (bid >= 6144) {  // wfT: 32 blocks x 256 thr x 8 elems = 65536
    int base = (bid - 6144) * 2048 + tid * 8;
#pragma unroll
    for (int ii = 0; ii < 8; ++ii) {
      int idx = base + ii;
      int side = idx >> 15, rem = idx & 32767;
      int k = rem >> 9, l = (rem >> 7) & 3, f = rem & 127;
      const float* src = side ? wyf : wxf;
      wfT[idx] = src[((size_t)l * 128 + f) * 64 + k];
    }
    return;
  }
  size_t i = ((size_t)(bid - 4096) * 256 + tid) * 8;
  const float* s; uint16_t* d;
  if (i < 2097152) { s = x + i;             d = xb + i; }
  else             { s = y + (i - 2097152); d = yb + (i - 2097152); }
  float4 v0 = *(const float4*)s;
  float4 v1 = *(const float4*)(s + 4);
  uint32_t o0 = (uint32_t)f2b(v0.x) | ((uint32_t)f2b(v0.y) << 16);
  uint32_t o1 = (uint32_t)f2b(v0.z) | ((uint32_t)f2b(v0.w) << 16);
  uint32_t o2 = (uint32_t)f2b(v1.x) | ((uint32_t)f2b(v1.y) << 16);
  uint32_t o3 = (uint32_t)f2b(v1.z) | ((uint32_t)f2b(v1.w) << 16);
  *(uint4*)d = make_uint4(o0, o1, o2, o3);
}

// ---------------------------------------------------------------------------
// K1: FUSED G-gen + split GEMM, 8 waves, counted-vmcnt pipeline (round-9
// proven kernel, 46.0 us). grid (64 groups, 8 M-tiles); group g:
// fb = g>>2 (8 fx), fyg = g&3 (32 fy). 32 steps, step t: fy = fyg*32 + t.
// ---------------------------------------------------------------------------
__device__ __forceinline__ void gload_lds16(const void* g, void* l) {
  __builtin_amdgcn_global_load_lds((const AS1 uint32_t*)g, (AS3 uint32_t*)l, 16, 0, 0);
}

#define PIPE_BAR(N) \
  asm volatile("s_waitcnt vmcnt(" #N ") lgkmcnt(0)\n\ts_barrier" ::: "memory")

__global__ __launch_bounds__(512, 4) void fused_gemm(
    const uint16_t* __restrict__ xb, const uint16_t* __restrict__ yb,
    const uint16_t* __restrict__ Wb2, float* __restrict__ Cpart) {
  __shared__ __align__(16) uint16_t sA[2][128 * 32];  // XOR slot swizzle
  __shared__ __align__(16) uint16_t sB[3][128 * 32];  // swizzle baked in Wb2
  __shared__ __align__(16) uint16_t yS[3][2048];      // [chunk(2)][m(128)][8c]

  int tid = threadIdx.x;
  int w = tid >> 6, lane = tid & 63;
  int g_id = blockIdx.x;            // 0..63
  int fb = g_id >> 2, fyg = g_id & 3;
  int FB = fb * 8;
  int fy0 = fyg * 32;
  int m0 = blockIdx.y * 128;
  int r = lane & 15, q = lane >> 4;
  int wm = w >> 2, wn = w & 3;      // 2 x 4 wave grid over 128x128 tile
  int m_loc = tid & 127, quarter = tid >> 7;

  // ---- one-time: x[m, FB+quarter*2 .. +2, 0:16] packed into 16 dwords
  uint32_t xr[16];
  {
    const uint16_t* xp0 = xb + (size_t)(m0 + m_loc) * 2048 + (FB + quarter * 2) * 16;
#pragma unroll
    for (int j = 0; j < 4; ++j) {
      uint4 v = *(const uint4*)(xp0 + j * 8);
      xr[j * 4 + 0] = v.x; xr[j * 4 + 1] = v.y;
      xr[j * 4 + 2] = v.z; xr[j * 4 + 3] = v.w;
    }
  }

  f32x4 zero = {0.f, 0.f, 0.f, 0.f};
  f32x4 acc[4][2];
#pragma unroll
  for (int i = 0; i < 4; ++i)
#pragma unroll
    for (int j = 0; j < 2; ++j) acc[i][j] = zero;

  // ---- DMA ownership: waves 0-3 stage B (2 loads), waves 4-7 stage Y (1).
  auto issueB = [&](uint16_t* dstB, int t) {
    if (w < 4) {
      size_t base = (size_t)(fb * 128 + fy0 + t) * 4096;  // halves
#pragma unroll
      for (int jj = 0; jj < 2; ++jj) {
        int blk = w * 2 + jj;  // wave-uniform
        gload_lds16(Wb2 + base + blk * 512 + lane * 8, dstB + blk * 512);
      }
    }
  };
  int ychunk = (w >> 1) & 1, ymbase = (w & 1) * 64;
  const uint16_t* ysrc_base = yb + (size_t)(m0 + ymbase + lane) * 2048 + ychunk * 8;
  int ydst_off = ychunk * 1024 + ymbase * 8;  // + lane*8 implied by DMA
  auto issueY = [&](uint16_t* dstY, int t) {
    if (w >= 4) gload_lds16(ysrc_base + (size_t)(fy0 + t) * 16, dstY + ydst_off);
  };

  auto computeG = [&](const uint16_t* srcY, float* gg) {
    uint4 ya = *(const uint4*)(srcY + m_loc * 8);
    uint4 yc = *(const uint4*)(srcY + 1024 + m_loc * 8);
    uint32_t yp[8] = {ya.x, ya.y, ya.z, ya.w, yc.x, yc.y, yc.z, yc.w};
    uint32_t yl0 = yp[0] & 0xffffu, yh0 = yp[0] & 0xffff0000u;
    uint32_t yl4 = yp[4] & 0xffffu, yh4 = yp[4] & 0xffff0000u;
#pragma unroll
    for (int fxp = 0; fxp < 2; ++fxp) {
      const uint32_t* xp = xr + fxp * 8;
      gg[fxp * 4 + 0] = dot2b(xp[0], yl0, 0.f);
      gg[fxp * 4 + 1] = dot2b(xp[1], yp[1], dot2b(xp[0], yh0, 0.f));
      gg[fxp * 4 + 2] = dot2b(xp[4], yl4,
                         dot2b(xp[3], yp[3], dot2b(xp[2], yp[2], 0.f)));
      gg[fxp * 4 + 3] = dot2b(xp[7], yp[7], dot2b(xp[6], yp[6],
                         dot2b(xp[5], yp[5], dot2b(xp[4], yh4, 0.f))));
    }
  };
  auto writeA = [&](uint16_t* dstA, const float* gg) {
    uint32_t o[4];
#pragma unroll
    for (int p = 0; p < 4; ++p)
      o[p] = (__float_as_uint(gg[2 * p]) >> 16) |
             (__float_as_uint(gg[2 * p + 1]) & 0xffff0000u);
    int pos = quarter ^ ((m_loc >> 1) & 3);   // XOR slot swizzle
    *(uint4*)(dstA + m_loc * 32 + pos * 8) = make_uint4(o[0], o[1], o[2], o[3]);
  };

  float gg[8];
  // ---- prologue: A(0) from Y(0); B0,B1,Y1,Y2 staged/in-flight.
  issueY(yS[0], 0);
  __syncthreads();                 // full drain: Y0 landed
  computeG(yS[0], gg);
  writeA(sA[0], gg);
  issueB(sB[0], 0);
  issueY(yS[1], 1);
  issueB(sB[1], 1);
  issueY(yS[2], 2);
  if (w < 4) PIPE_BAR(2); else PIPE_BAR(1);  // drain B0 / Y1; keep B1 / Y2

  uint16_t *pAc = sA[0], *pAn = sA[1];
  uint16_t *pBread = sB[0], *pBmid = sB[1], *pBissue = sB[2];
  uint16_t *pYcomp = yS[1], *pYmid = yS[2], *pYissue = yS[0];

  for (int t = 0; t < 32; ++t) {
    if (t <= 29) issueB(pBissue, t + 2);
    if (t <= 28) issueY(pYissue, t + 3);

    bf16x8 a[4], b[2];
#pragma unroll
    for (int i = 0; i < 4; ++i) {
      int row = wm * 64 + i * 16 + r;
      int pos = q ^ ((row >> 1) & 3);
      a[i] = *(const bf16x8*)&pAc[row * 32 + pos * 8];
    }
#pragma unroll
    for (int j = 0; j < 2; ++j) {
      int row = wn * 32 + j * 16 + r;
      int pos = q ^ ((row >> 1) & 3);
      b[j] = *(const bf16x8*)&pBread[row * 32 + pos * 8];
    }

    if (t < 31) {                 // produce A(t+1) from Y(t+1)
      computeG(pYcomp, gg);
      writeA(pAn, gg);
    }

    __builtin_amdgcn_s_setprio(1);
#pragma unroll
    for (int i = 0; i < 4; ++i)
#pragma unroll
      for (int j = 0; j < 2; ++j)
        acc[i][j] = __builtin_amdgcn_mfma_f32_16x16x32_bf16(a[i], b[j], acc[i][j], 0, 0, 0);
    __builtin_amdgcn_s_setprio(0);

    if (t <= 28)      { if (w < 4) PIPE_BAR(2); else PIPE_BAR(1); }
    else if (t == 29) { if (w < 4) PIPE_BAR(2); else PIPE_BAR(0); }
    else if (t == 30) PIPE_BAR(0);
    // t == 31: no barrier; straight to epilogue

    uint16_t* tp;
    tp = pAc; pAc = pAn; pAn = tp;
    tp = pBread; pBread = pBmid; pBmid = pBissue; pBissue = tp;
    tp = pYcomp; pYcomp = pYmid; pYmid = pYissue; pYissue = tp;
  }

  // C/D layout: col(n)=lane&15, row(m)=(lane>>4)*4+reg
  // Cpart layout [bm][sp][n]: same per-instruction coalescing as before
  // (4 x 64B segments), but finish_kernel reads become contiguous.
#pragma unroll
  for (int i = 0; i < 4; ++i)
#pragma unroll
    for (int j = 0; j < 2; ++j)
#pragma unroll
      for (int reg = 0; reg < 4; ++reg) {
        int mm = m0 + wm * 64 + i * 16 + q * 4 + reg;
        int nn = wn * 32 + j * 16 + r;
        Cpart[((size_t)mm * 64 + g_id) * 128 + nn] = acc[i][j][reg];
      }
}

// ---------------------------------------------------------------------------
// K2: ONE BLOCK PER bm: contiguous 32KB split-K reduce, MLP, gates, output.
// ---------------------------------------------------------------------------
__global__ __launch_bounds__(256) void finish_kernel(
    const float* __restrict__ x, const float* __restrict__ y,
    const float* __restrict__ wx_mlp, const float* __restrict__ bx_mlp,
    const float* __restrict__ wy_mlp, const float* __restrict__ by_mlp,
    const float* __restrict__ wfT,
    const float* __restrict__ Cpart, float* __restrict__ out) {
  const int seg[16] = {0,1,1,1,2,2,2,2,2,3,3,3,3,3,3,3};
  __shared__ float sred[256];
  __shared__ float sm[128];
  __shared__ float sg[2][128][4];
  int t = threadIdx.x;
  int bm = blockIdx.x;
  int mi = bm & 63;

  {  // split-K reduction: sm[n] = sum_{sp<64} Cpart[bm][sp][n] (contiguous)
    int col = t & 127, hh = t >> 7;
    const float* cp = Cpart + ((size_t)bm * 64 + hh * 32) * 128 + col;
    float s = 0.f;
#pragma unroll 8
    for (int sp = 0; sp < 32; ++sp)
      s += cp[(size_t)sp * 128];
    sred[t] = s;
  }
  __syncthreads();
  if (t < 128) sm[t] = sred[t] + sred[t + 128];  // [0:64)=mx, [64:128)=my
  __syncthreads();

  for (int st = 0; st < 2; ++st) {
    float v = 0.f;
    if (t < 128) {
      int side = t >> 6, j = t & 63;
      const float* wmlp = side ? wy_mlp : wx_mlp;
      const float* bmlp = side ? by_mlp : bx_mlp;
      const float* mv = sm + side * 64;
#pragma unroll 8
      for (int k = 0; k < 64; ++k)
        v += mv[k] * wmlp[(st * 64 + k) * 64 + j];
      v += bmlp[(st * 64 + mi) * 64 + j];
      v = v / (1.f + __expf(-v));
    }
    __syncthreads();
    if (t < 128) sm[t] = v;
    __syncthreads();
  }

  {  // gates: side wave-uniform, coalesced wfT reads
    int side = t >> 7, f = t & 127;
    const float* base = wfT + side * 32768;  // [k][l][f]
    const float* mv = sm + side * 64;
    float gg[4] = {0.f, 0.f, 0.f, 0.f};
#pragma unroll 8
    for (int k = 0; k < 64; ++k) {
      float m2 = mv[k];
#pragma unroll
      for (int l = 0; l < 4; ++l)
        gg[l] += m2 * base[(k * 4 + l) * 128 + f];
    }
#pragma unroll
    for (int l = 0; l < 4; ++l)
      sg[side][f][l] = gg[l] / (1.f + __expf(-gg[l]));
  }
  __syncthreads();

  {  // output: thread -> (f, half), 8 floats; fully coalesced
    int f = t >> 1, half = t & 1;
    size_t base = ((size_t)bm * 128 + f) * 16 + half * 8;
    float4 xa = *(const float4*)(x + base), xb4 = *(const float4*)(x + base + 4);
    float4 ya = *(const float4*)(y + base), yb4 = *(const float4*)(y + base + 4);
    float xv[8] = {xa.x, xa.y, xa.z, xa.w, xb4.x, xb4.y, xb4.z, xb4.w};
    float yv[8] = {ya.x, ya.y, ya.z, ya.w, yb4.x, yb4.y, yb4.z, yb4.w};
    float o[8];
#pragma unroll
    for (int ii = 0; ii < 8; ++ii) {
      int c = half * 8 + ii;
      o[ii] = sg[0][f][seg[c]] * xv[ii] + sg[1][f][seg[c]] * yv[ii];
    }
    *(float4*)(out + base)     = make_float4(o[0], o[1], o[2], o[3]);
    *(float4*)(out + base + 4) = make_float4(o[4], o[5], o[6], o[7]);
  }
}

// ---------------------------------------------------------------------------
extern "C" void kernel_launch(void* const* d_in, const int* in_sizes, int n_in,
                              void* d_out, int out_size, void* d_ws, size_t ws_size,
                              hipStream_t stream) {
  const float* x      = (const float*)d_in[0];
  const float* y      = (const float*)d_in[1];
  const float* wx0    = (const float*)d_in[2];
  const float* wy0    = (const float*)d_in[3];
  const float* wx_mlp = (const float*)d_in[4];
  const float* bx_mlp = (const float*)d_in[5];
  const float* wy_mlp = (const float*)d_in[6];
  const float* by_mlp = (const float*)d_in[7];
  const float* wxf    = (const float*)d_in[8];
  const float* wyf    = (const float*)d_in[9];
  float* out = (float*)d_out;

  uint16_t* Wb2   = (uint16_t*)d_ws;                               // 16,777,216 B
  uint16_t* xb    = (uint16_t*)((char*)d_ws + (size_t)16777216);   //  4,194,304 B
  uint16_t* yb    = (uint16_t*)((char*)d_ws + (size_t)20971520);   //  4,194,304 B
  float*    Cpart = (float*)((char*)d_ws + (size_t)25165824);      // 33,554,432 B
  float*    wfT   = (float*)((char*)d_ws + (size_t)58720256);      //    262,144 B

  convert_all<<<6176, 256, 0, stream>>>(wx0, wy0, x, y, wxf, wyf, Wb2, xb, yb, wfT);
  fused_gemm<<<dim3(64, 8), 512, 0, stream>>>(xb, yb, Wb2, Cpart);
  finish_kernel<<<1024, 256, 0, stream>>>(x, y, wx_mlp, bx_mlp, wy_mlp, by_mlp,
                                          wfT, Cpart, out);
}

// Round 8
// 162.804 us; speedup vs baseline: 2.3210x; 1.0201x over previous
//
#include <hip/hip_runtime.h>
#include <stdint.h>

// ---------------------------------------------------------------------------
// MixingLayer: b=16, m=64, f=128, k=64, L2=16, LMAX=4. ALL I/O IS FP32.
// SEG = [0,1,1,1,2,2,2,2,2,3,3,3,3,3,3,3]
//
// Round-15: y REMOVED FROM LDS (the R7 counters show the LDS issue pipe is
// the saturated resource: ~1700 cyc of b128 slots per CU-step vs 1437 wall).
//   * ybT[fy][m][16] (transposed at convert): per step each thread loads its
//     32B y row via 2 coalesced global dwordx4 into REGISTERS (named double
//     buffer, loaded 2 steps ahead; compiler-inserted waits). Removes 16
//     LDS-read instr + Y-DMA per block-step and the 12KB yS buffer.
//   * LDS = sA[2]+sB[3] = 40,960 B -> 4 blocks/CU (LDS cap). VGPR target
//     <=64 for the 32-wave cliff (R7 was 56; +8 y regs -3 freed pointers).
//   * Queue discipline: per step, order pinned by sched_barrier(0):
//     [issueB x2 (w<4)] | SB0 | ds a/b + computeG + y-reload | SB0 | MFMA |
//     PIPE_BAR.  Steady bars: w<4 vmcnt(6) (keeps B(t+2)+y(t+3) in flight,
//     retires B(t+1)); w>=4 vmcnt(4). Tails: t=29 ->4, t=30 ->0. Verified by
//     full in-order queue trace (prologue, steady, 28/29/30/31).
//   * Everything else (computeG math, writeA swizzle, a/b reads, Wb2 blocked
//     layout, Cpart [bm][sp][n], finish) identical to R7 (45.5 us, passed).
//
// ws layout (bytes):
//   Wb2 bf16 [16fb][128fy][128n][32] @ 0        (16,777,216)
//   xb  bf16 [1024 m][128 f][16] @ 16777216     ( 4,194,304)
//   ybT bf16 [128 fy][1024 m][16] @ 20971520    ( 4,194,304)
//   Cpart f32 [1024 bm][64 sp][128 n] @ 25165824 (33,554,432)
//   wfT f32 [2][64 k][4 l][128f] @ 58720256     (   262,144)
// ---------------------------------------------------------------------------

#define AS1 __attribute__((address_space(1)))
#define AS3 __attribute__((address_space(3)))

typedef __bf16 bf16x8 __attribute__((ext_vector_type(8)));
typedef float f32x4 __attribute__((ext_vector_type(4)));

__device__ __forceinline__ uint16_t f2b(float f) {
  uint32_t u = __float_as_uint(f);
  u += 0x7fffu + ((u >> 16) & 1u);   // RNE
  return (uint16_t)(u >> 16);
}

#if __has_builtin(__builtin_amdgcn_fdot2_f32_bf16)
typedef __bf16 bf16x2 __attribute__((ext_vector_type(2)));
__device__ __forceinline__ float dot2b(uint32_t a, uint32_t b, float c) {
  union { uint32_t u; bf16x2 v; } ua, ub;
  ua.u = a; ub.u = b;
  return __builtin_amdgcn_fdot2_f32_bf16(ua.v, ub.v, c, false);
}
#else
__device__ __forceinline__ float dot2b(uint32_t a, uint32_t b, float c) {
  float a0 = __uint_as_float(a << 16), a1 = __uint_as_float(a & 0xffff0000u);
  float b0 = __uint_as_float(b << 16), b1 = __uint_as_float(b & 0xffff0000u);
  return c + a0 * b0 + a1 * b1;
}
#endif

// ---------------------------------------------------------------------------
// K0: Wb2 (blocked, swizzle-baked) + xb + ybT (transposed) + wfT.
// grid: [0,4096) Wb2 ; [4096,5120) xb ; [5120,6144) ybT ; [6144,6176) wfT.
// ---------------------------------------------------------------------------
__global__ __launch_bounds__(256) void convert_all(
    const float* __restrict__ wx0, const float* __restrict__ wy0,
    const float* __restrict__ x, const float* __restrict__ y,
    const float* __restrict__ wxf, const float* __restrict__ wyf,
    uint16_t* __restrict__ Wb2, uint16_t* __restrict__ xb,
    uint16_t* __restrict__ ybT, float* __restrict__ wfT) {
  int bid = blockIdx.x, tid = threadIdx.x;
  if (bid < 4096) {  // Wb2: 1,048,576 chunks of 8 halves
    int c = bid * 256 + tid;
    int fb = c >> 16;
    int rem = c & 65535;
    int fy = rem >> 9;
    int rem2 = rem & 511;
    int n = rem2 >> 2, pos = rem2 & 3;
    int slot = pos ^ ((n >> 1) & 3);   // bake the sB read swizzle
    int k = n & 63;
    const float* src = (n < 64 ? wx0 : wy0) +
        ((size_t)(k * 128 + fy) * 512 + fb * 32 + slot * 8);
    float4 v0 = *(const float4*)src;
    float4 v1 = *(const float4*)(src + 4);
    uint32_t o0 = (uint32_t)f2b(v0.x) | ((uint32_t)f2b(v0.y) << 16);
    uint32_t o1 = (uint32_t)f2b(v0.z) | ((uint32_t)f2b(v0.w) << 16);
    uint32_t o2 = (uint32_t)f2b(v1.x) | ((uint32_t)f2b(v1.y) << 16);
    uint32_t o3 = (uint32_t)f2b(v1.z) | ((uint32_t)f2b(v1.w) << 16);
    *(uint4*)(Wb2 + (size_t)c * 8) = make_uint4(o0, o1, o2, o3);
    return;
  }
  if (bid >= 6144) {  // wfT: 32 blocks x 256 thr x 8 elems = 65536
    int base = (bid - 6144) * 2048 + tid * 8;
#pragma unroll
    for (int ii = 0; ii < 8; ++ii) {
      int idx = base + ii;
      int side = idx >> 15, rem = idx & 32767;
      int k = rem >> 9, l = (rem >> 7) & 3, f = rem & 127;
      const float* src = side ? wyf : wxf;
      wfT[idx] = src[((size_t)l * 128 + f) * 64 + k];
    }
    return;
  }
  if (bid < 5120) {  // xb: straight bf16 convert, layout [m][f][16c]
    size_t i = ((size_t)(bid - 4096) * 256 + tid) * 8;
    const float* s = x + i;
    float4 v0 = *(const float4*)s;
    float4 v1 = *(const float4*)(s + 4);
    uint32_t o0 = (uint32_t)f2b(v0.x) | ((uint32_t)f2b(v0.y) << 16);
    uint32_t o1 = (uint32_t)f2b(v0.z) | ((uint32_t)f2b(v0.w) << 16);
    uint32_t o2 = (uint32_t)f2b(v1.x) | ((uint32_t)f2b(v1.y) << 16);
    uint32_t o3 = (uint32_t)f2b(v1.z) | ((uint32_t)f2b(v1.w) << 16);
    *(uint4*)(xb + i) = make_uint4(o0, o1, o2, o3);
    return;
  }
  {  // ybT[fy][m][16c] <- y[m][fy][16c]  (verified mapping, R3/R12)
    int c = (bid - 5120) * 256 + tid;      // unit = (m*128+fy)*2 + half
    int half = c & 1, fy = (c >> 1) & 127, m = c >> 8;
    const float* s = y + (size_t)c * 8;
    float4 v0 = *(const float4*)s;
    float4 v1 = *(const float4*)(s + 4);
    uint32_t o0 = (uint32_t)f2b(v0.x) | ((uint32_t)f2b(v0.y) << 16);
    uint32_t o1 = (uint32_t)f2b(v0.z) | ((uint32_t)f2b(v0.w) << 16);
    uint32_t o2 = (uint32_t)f2b(v1.x) | ((uint32_t)f2b(v1.y) << 16);
    uint32_t o3 = (uint32_t)f2b(v1.z) | ((uint32_t)f2b(v1.w) << 16);
    *(uint4*)(ybT + ((size_t)fy * 1024 + m) * 16 + half * 8) =
        make_uint4(o0, o1, o2, o3);
  }
}

// ---------------------------------------------------------------------------
// K1: FUSED G-gen + split GEMM, 8 waves, y-in-registers, counted vmcnt.
// grid (64 groups, 8 M-tiles); group g: fb = g>>2, fyg = g&3 (32 fy).
// 32 steps, step t: fy = fyg*32 + t.  LDS 40,960 B.
// ---------------------------------------------------------------------------
__device__ __forceinline__ void gload_lds16(const void* g, void* l) {
  __builtin_amdgcn_global_load_lds((const AS1 uint32_t*)g, (AS3 uint32_t*)l, 16, 0, 0);
}

#define SB0 __builtin_amdgcn_sched_barrier(0)
#define PIPE_BAR(N) \
  asm volatile("s_waitcnt vmcnt(" #N ") lgkmcnt(0)\n\ts_barrier" ::: "memory")

__global__ __launch_bounds__(512, 4) void fused_gemm(
    const uint16_t* __restrict__ xb, const uint16_t* __restrict__ ybT,
    const uint16_t* __restrict__ Wb2, float* __restrict__ Cpart) {
  __shared__ __align__(16) uint16_t sA[2][128 * 32];  // XOR slot swizzle
  __shared__ __align__(16) uint16_t sB[3][128 * 32];  // swizzle baked in Wb2

  int tid = threadIdx.x;
  int w = tid >> 6, lane = tid & 63;
  int g_id = blockIdx.x;            // 0..63
  int fb = g_id >> 2, fyg = g_id & 3;
  int FB = fb * 8;
  int fy0 = fyg * 32;
  int m0 = blockIdx.y * 128;
  int r = lane & 15, q = lane >> 4;
  int wm = w >> 2, wn = w & 3;      // 2 x 4 wave grid over 128x128 tile
  int m_loc = tid & 127, quarter = tid >> 7;

  // ---- one-time: x[m, FB+quarter*2 .. +2, 0:16] packed into 16 dwords
  uint32_t xr[16];
  {
    const uint16_t* xp0 = xb + (size_t)(m0 + m_loc) * 2048 + (FB + quarter * 2) * 16;
#pragma unroll
    for (int j = 0; j < 4; ++j) {
      uint4 v = *(const uint4*)(xp0 + j * 8);
      xr[j * 4 + 0] = v.x; xr[j * 4 + 1] = v.y;
      xr[j * 4 + 2] = v.z; xr[j * 4 + 3] = v.w;
    }
  }

  f32x4 zero = {0.f, 0.f, 0.f, 0.f};
  f32x4 acc[4][2];
#pragma unroll
  for (int i = 0; i < 4; ++i)
#pragma unroll
    for (int j = 0; j < 2; ++j) acc[i][j] = zero;

  // ---- B DMA: waves 0-3 stage 2x1KB chunks per step.
  auto issueB = [&](uint16_t* dstB, int t) {
    if (w < 4) {
      size_t base = (size_t)(fb * 128 + fy0 + t) * 4096;  // halves
#pragma unroll
      for (int jj = 0; jj < 2; ++jj) {
        int blk = w * 2 + jj;  // wave-uniform
        gload_lds16(Wb2 + base + blk * 512 + lane * 8, dstB + blk * 512);
      }
    }
  };

  // ---- y base: ybT[fy][m][16] -> per-thread coalesced 32B row reads.
  const uint16_t* ybase = ybT + (size_t)(m0 + m_loc) * 16;

  auto computeG = [&](uint4 ya, uint4 yc, float* gg) {
    uint32_t yp[8] = {ya.x, ya.y, ya.z, ya.w, yc.x, yc.y, yc.z, yc.w};
    uint32_t yl0 = yp[0] & 0xffffu, yh0 = yp[0] & 0xffff0000u;
    uint32_t yl4 = yp[4] & 0xffffu, yh4 = yp[4] & 0xffff0000u;
#pragma unroll
    for (int fxp = 0; fxp < 2; ++fxp) {
      const uint32_t* xp = xr + fxp * 8;
      gg[fxp * 4 + 0] = dot2b(xp[0], yl0, 0.f);
      gg[fxp * 4 + 1] = dot2b(xp[1], yp[1], dot2b(xp[0], yh0, 0.f));
      gg[fxp * 4 + 2] = dot2b(xp[4], yl4,
                         dot2b(xp[3], yp[3], dot2b(xp[2], yp[2], 0.f)));
      gg[fxp * 4 + 3] = dot2b(xp[7], yp[7], dot2b(xp[6], yp[6],
                         dot2b(xp[5], yp[5], dot2b(xp[4], yh4, 0.f))));
    }
  };
  auto writeA = [&](uint16_t* dstA, const float* gg) {
    uint32_t o[4];
#pragma unroll
    for (int p = 0; p < 4; ++p)
      o[p] = (__float_as_uint(gg[2 * p]) >> 16) |
             (__float_as_uint(gg[2 * p + 1]) & 0xffff0000u);
    int pos = quarter ^ ((m_loc >> 1) & 3);   // XOR slot swizzle
    *(uint4*)(dstA + m_loc * 32 + pos * 8) = make_uint4(o[0], o[1], o[2], o[3]);
  };

  uint16_t *pAc = sA[0], *pAn = sA[1];
  uint16_t *pBread = sB[0], *pBmid = sB[1], *pBissue = sB[2];

  float gg[8];
  // ---- prologue: B(0),B(1) DMAs first; y(0) temp; A(0); y(1),y(2) in regs.
  issueB(pBread, 0);
  issueB(pBmid, 1);
  SB0;
  uint4 yev0, yev1, yod0, yod1;
  {
    const uint16_t* yp0 = ybase + (size_t)fy0 * 16384;
    uint4 t0a = *(const uint4*)yp0;
    uint4 t0b = *(const uint4*)(yp0 + 8);
    computeG(t0a, t0b, gg);         // compiler wait drains B0,B1,t0
    writeA(pAc, gg);
    yev0 = *(const uint4*)(ybase + (size_t)(fy0 + 1) * 16384);
    yev1 = *(const uint4*)(ybase + (size_t)(fy0 + 1) * 16384 + 8);
    yod0 = *(const uint4*)(ybase + (size_t)(fy0 + 2) * 16384);
    yod1 = *(const uint4*)(ybase + (size_t)(fy0 + 2) * 16384 + 8);
  }
  SB0;
  PIPE_BAR(4);                       // keep yev,yod in flight; B0/A0 visible

  // ---- step body. Step t: reads A(t)/B(t); computeG->A(t+1) from y(t+1)
  //      held in (y0_,y1_); reloads (y0_,y1_) <- y(t+3).
  auto body = [&](int t, uint4& y0_, uint4& y1_) {
    if (t <= 29) issueB(pBissue, t + 2);
    SB0;
    bf16x8 a[4], b[2];
#pragma unroll
    for (int i = 0; i < 4; ++i) {
      int row = wm * 64 + i * 16 + r;
      int pos = q ^ ((row >> 1) & 3);
      a[i] = *(const bf16x8*)&pAc[row * 32 + pos * 8];
    }
#pragma unroll
    for (int j = 0; j < 2; ++j) {
      int row = wn * 32 + j * 16 + r;
      int pos = q ^ ((row >> 1) & 3);
      b[j] = *(const bf16x8*)&pBread[row * 32 + pos * 8];
    }
    if (t < 31) {                    // produce A(t+1) from y(t+1) regs
      computeG(y0_, y1_, gg);
      writeA(pAn, gg);
    }
    if (t <= 28) {                   // reload y(t+3) (WAR after computeG)
      y0_ = *(const uint4*)(ybase + (size_t)(fy0 + t + 3) * 16384);
      y1_ = *(const uint4*)(ybase + (size_t)(fy0 + t + 3) * 16384 + 8);
    }
    SB0;
    __builtin_amdgcn_s_setprio(1);
#pragma unroll
    for (int i = 0; i < 4; ++i)
#pragma unroll
      for (int j = 0; j < 2; ++j)
        acc[i][j] = __builtin_amdgcn_mfma_f32_16x16x32_bf16(a[i], b[j], acc[i][j], 0, 0, 0);
    __builtin_amdgcn_s_setprio(0);

    // In-order queue trace (w<4, steady): after-B(t+1) =
    // [y(t+2)^2, B(t+2)^2, y(t+3)^2] = 6.  w>=4: y pairs only = 4.
    if (t <= 28)      { if (w < 4) PIPE_BAR(6); else PIPE_BAR(4); }
    else if (t == 29) { if (w < 4) PIPE_BAR(4); else PIPE_BAR(4); }
    else if (t == 30) PIPE_BAR(0);
    // t == 31: no barrier; straight to epilogue

    uint16_t* tp;
    tp = pAc; pAc = pAn; pAn = tp;
    tp = pBread; pBread = pBmid; pBmid = pBissue; pBissue = tp;
  };

  for (int t = 0; t < 32; t += 2) {
    body(t, yev0, yev1);             // even steps consume y(t+1) (odd idx)
    body(t + 1, yod0, yod1);         // odd steps consume y(t+1) (even idx)
  }

  // C/D layout: col(n)=lane&15, row(m)=(lane>>4)*4+reg
  // Cpart layout [bm][sp][n] (finish reads contiguous).
#pragma unroll
  for (int i = 0; i < 4; ++i)
#pragma unroll
    for (int j = 0; j < 2; ++j)
#pragma unroll
      for (int reg = 0; reg < 4; ++reg) {
        int mm = m0 + wm * 64 + i * 16 + q * 4 + reg;
        int nn = wn * 32 + j * 16 + r;
        Cpart[((size_t)mm * 64 + g_id) * 128 + nn] = acc[i][j][reg];
      }
}

// ---------------------------------------------------------------------------
// K2: ONE BLOCK PER bm: contiguous 32KB split-K reduce, MLP, gates, output.
// ---------------------------------------------------------------------------
__global__ __launch_bounds__(256) void finish_kernel(
    const float* __restrict__ x, const float* __restrict__ y,
    const float* __restrict__ wx_mlp, const float* __restrict__ bx_mlp,
    const float* __restrict__ wy_mlp, const float* __restrict__ by_mlp,
    const float* __restrict__ wfT,
    const float* __restrict__ Cpart, float* __restrict__ out) {
  const int seg[16] = {0,1,1,1,2,2,2,2,2,3,3,3,3,3,3,3};
  __shared__ float sred[256];
  __shared__ float sm[128];
  __shared__ float sg[2][128][4];
  int t = threadIdx.x;
  int bm = blockIdx.x;
  int mi = bm & 63;

  {  // split-K reduction: sm[n] = sum_{sp<64} Cpart[bm][sp][n] (contiguous)
    int col = t & 127, hh = t >> 7;
    const float* cp = Cpart + ((size_t)bm * 64 + hh * 32) * 128 + col;
    float s = 0.f;
#pragma unroll 8
    for (int sp = 0; sp < 32; ++sp)
      s += cp[(size_t)sp * 128];
    sred[t] = s;
  }
  __syncthreads();
  if (t < 128) sm[t] = sred[t] + sred[t + 128];  // [0:64)=mx, [64:128)=my
  __syncthreads();

  for (int st = 0; st < 2; ++st) {
    float v = 0.f;
    if (t < 128) {
      int side = t >> 6, j = t & 63;
      const float* wmlp = side ? wy_mlp : wx_mlp;
      const float* bmlp = side ? by_mlp : bx_mlp;
      const float* mv = sm + side * 64;
#pragma unroll 8
      for (int k = 0; k < 64; ++k)
        v += mv[k] * wmlp[(st * 64 + k) * 64 + j];
      v += bmlp[(st * 64 + mi) * 64 + j];
      v = v / (1.f + __expf(-v));
    }
    __syncthreads();
    if (t < 128) sm[t] = v;
    __syncthreads();
  }

  {  // gates: side wave-uniform, coalesced wfT reads
    int side = t >> 7, f = t & 127;
    const float* base = wfT + side * 32768;  // [k][l][f]
    const float* mv = sm + side * 64;
    float gg[4] = {0.f, 0.f, 0.f, 0.f};
#pragma unroll 8
    for (int k = 0; k < 64; ++k) {
      float m2 = mv[k];
#pragma unroll
      for (int l = 0; l < 4; ++l)
        gg[l] += m2 * base[(k * 4 + l) * 128 + f];
    }
#pragma unroll
    for (int l = 0; l < 4; ++l)
      sg[side][f][l] = gg[l] / (1.f + __expf(-gg[l]));
  }
  __syncthreads();

  {  // output: thread -> (f, half), 8 floats; fully coalesced
    int f = t >> 1, half = t & 1;
    size_t base = ((size_t)bm * 128 + f) * 16 + half * 8;
    float4 xa = *(const float4*)(x + base), xb4 = *(const float4*)(x + base + 4);
    float4 ya = *(const float4*)(y + base), yb4 = *(const float4*)(y + base + 4);
    float xv[8] = {xa.x, xa.y, xa.z, xa.w, xb4.x, xb4.y, xb4.z, xb4.w};
    float yv[8] = {ya.x, ya.y, ya.z, ya.w, yb4.x, yb4.y, yb4.z, yb4.w};
    float o[8];
#pragma unroll
    for (int ii = 0; ii < 8; ++ii) {
      int c = half * 8 + ii;
      o[ii] = sg[0][f][seg[c]] * xv[ii] + sg[1][f][seg[c]] * yv[ii];
    }
    *(float4*)(out + base)     = make_float4(o[0], o[1], o[2], o[3]);
    *(float4*)(out + base + 4) = make_float4(o[4], o[5], o[6], o[7]);
  }
}

// ---------------------------------------------------------------------------
extern "C" void kernel_launch(void* const* d_in, const int* in_sizes, int n_in,
                              void* d_out, int out_size, void* d_ws, size_t ws_size,
                              hipStream_t stream) {
  const float* x      = (const float*)d_in[0];
  const float* y      = (const float*)d_in[1];
  const float* wx0    = (const float*)d_in[2];
  const float* wy0    = (const float*)d_in[3];
  const float* wx_mlp = (const float*)d_in[4];
  const float* bx_mlp = (const float*)d_in[5];
  const float* wy_mlp = (const float*)d_in[6];
  const float* by_mlp = (const float*)d_in[7];
  const float* wxf    = (const float*)d_in[8];
  const float* wyf    = (const float*)d_in[9];
  float* out = (float*)d_out;

  uint16_t* Wb2   = (uint16_t*)d_ws;                               // 16,777,216 B
  uint16_t* xb    = (uint16_t*)((char*)d_ws + (size_t)16777216);   //  4,194,304 B
  uint16_t* ybT   = (uint16_t*)((char*)d_ws + (size_t)20971520);   //  4,194,304 B
  float*    Cpart = (float*)((char*)d_ws + (size_t)25165824);      // 33,554,432 B
  float*    wfT   = (float*)((char*)d_ws + (size_t)58720256);      //    262,144 B

  convert_all<<<6176, 256, 0, stream>>>(wx0, wy0, x, y, wxf, wyf, Wb2, xb, ybT, wfT);
  fused_gemm<<<dim3(64, 8), 512, 0, stream>>>(xb, ybT, Wb2, Cpart);
  finish_kernel<<<1024, 256, 0, stream>>>(x, y, wx_mlp, bx_mlp, wy_mlp, by_mlp,
                                          wfT, Cpart, out);
}